// Round 1
// baseline (197.180 us; speedup 1.0000x reference)
//
#include <hip/hip_runtime.h>
#include <hip/hip_bf16.h>

#define NUM_NODES 1000000
#define MEMORY_DIM 128
#define N_IDS_EXPECTED 500000

// One row = 128 f32 = 512 B = 32 x float4. Assign 32 threads per row:
// lane i loads float4 i of the row. Fully coalesced 512B segment per row
// for both gather-read and sequential write.
__global__ void tgn_gather_kernel(const int* __restrict__ n_id,
                                  const float4* __restrict__ mem,      // [NUM_NODES*32]
                                  const float4* __restrict__ pos,      // [NUM_NODES*32]
                                  const int* __restrict__ last,        // [NUM_NODES]
                                  float4* __restrict__ z_out,          // [n*32]
                                  float4* __restrict__ pz_out,         // [n*32]
                                  float* __restrict__ lu_out,          // [n] (as float)
                                  int n) {
    const int tid  = blockIdx.x * blockDim.x + threadIdx.x;
    const int lane = tid & 31;   // which float4 within the row
    const int row0 = tid >> 5;   // row index
    const int rstride = (gridDim.x * blockDim.x) >> 5;

    for (int r = row0; r < n; r += rstride) {
        const int id = n_id[r];                       // broadcast within 32-lane group (L1 hit)
        const size_t src = (size_t)id * 32 + lane;
        const size_t dst = (size_t)r  * 32 + lane;
        z_out[dst]  = mem[src];
        pz_out[dst] = pos[src];
        if (lane == 0) lu_out[r] = (float)last[id];
    }
}

extern "C" void kernel_launch(void* const* d_in, const int* in_sizes, int n_in,
                              void* d_out, int out_size, void* d_ws, size_t ws_size,
                              hipStream_t stream) {
    const int*   n_id = (const int*)d_in[0];
    const float* memb = (const float*)d_in[1];
    const float* posb = (const float*)d_in[2];
    const int*   lub  = (const int*)d_in[3];
    const int n = in_sizes[0];   // 500000

    float* z_out  = (float*)d_out;                               // n*128
    float* pz_out = z_out + (size_t)n * MEMORY_DIM;              // n*128
    float* lu_out = pz_out + (size_t)n * MEMORY_DIM;             // n

    const int block = 256;                       // 8 rows per block
    const long long total_threads = (long long)n * 32;
    int grid = (int)((total_threads + block - 1) / block);       // 62500

    tgn_gather_kernel<<<grid, block, 0, stream>>>(
        n_id,
        (const float4*)memb, (const float4*)posb, lub,
        (float4*)z_out, (float4*)pz_out, lu_out, n);
}

// Round 3
// 163.286 us; speedup vs baseline: 1.2076x; 1.2076x over previous
//
#include <hip/hip_runtime.h>
#include <hip/hip_bf16.h>

#define NUM_NODES 1000000
#define MEMORY_DIM 128

typedef float floatx4 __attribute__((ext_vector_type(4)));

// One row = 128 f32 = 512 B = 32 x float4. 32 threads per row: lane i
// handles float4 i. Fully coalesced 512B segment per row for gather-read
// and sequential write. Outputs are written with non-temporal stores so
// the 514 MB output stream doesn't evict gathered bank rows from L2/L3
// (duplicate ids ~21% of accesses should re-hit cache).
__global__ void tgn_gather_kernel(const int* __restrict__ n_id,
                                  const floatx4* __restrict__ mem,     // [NUM_NODES*32]
                                  const floatx4* __restrict__ pos,     // [NUM_NODES*32]
                                  const int* __restrict__ last,        // [NUM_NODES]
                                  floatx4* __restrict__ z_out,         // [n*32]
                                  floatx4* __restrict__ pz_out,        // [n*32]
                                  float* __restrict__ lu_out,          // [n] (as float)
                                  int n) {
    const int tid  = blockIdx.x * blockDim.x + threadIdx.x;
    const int lane = tid & 31;   // which float4 within the row
    const int r    = tid >> 5;   // row index
    if (r >= n) return;

    const int id = n_id[r];                       // broadcast within 32-lane group
    const size_t src = (size_t)id * 32 + lane;
    const size_t dst = (size_t)r  * 32 + lane;

    const floatx4 zv  = mem[src];
    const floatx4 pzv = pos[src];
    __builtin_nontemporal_store(zv,  &z_out[dst]);
    __builtin_nontemporal_store(pzv, &pz_out[dst]);
    if (lane == 0) {
        __builtin_nontemporal_store((float)last[id], &lu_out[r]);
    }
}

extern "C" void kernel_launch(void* const* d_in, const int* in_sizes, int n_in,
                              void* d_out, int out_size, void* d_ws, size_t ws_size,
                              hipStream_t stream) {
    const int*   n_id = (const int*)d_in[0];
    const float* memb = (const float*)d_in[1];
    const float* posb = (const float*)d_in[2];
    const int*   lub  = (const int*)d_in[3];
    const int n = in_sizes[0];   // 500000

    float* z_out  = (float*)d_out;                               // n*128
    float* pz_out = z_out + (size_t)n * MEMORY_DIM;              // n*128
    float* lu_out = pz_out + (size_t)n * MEMORY_DIM;             // n

    const int block = 256;                       // 8 rows per block
    const long long total_threads = (long long)n * 32;
    int grid = (int)((total_threads + block - 1) / block);       // 62500

    tgn_gather_kernel<<<grid, block, 0, stream>>>(
        n_id,
        (const floatx4*)memb, (const floatx4*)posb, lub,
        (floatx4*)z_out, (floatx4*)pz_out, lu_out, n);
}